// Round 8
// baseline (79.517 us; speedup 1.0000x reference)
//
#include <hip/hip_runtime.h>
#include <hip/hip_bf16.h>

#define EPS 1e-3f

typedef float f32x4 __attribute__((ext_vector_type(4)));
typedef float f4    __attribute__((ext_vector_type(4)));
typedef short short8 __attribute__((ext_vector_type(8)));

__device__ __forceinline__ unsigned short f2bf(float f) {
    unsigned u = __float_as_uint(f);
    u += 0x7FFFu + ((u >> 16) & 1u);   // round-to-nearest-even
    return (unsigned short)(u >> 16);
}
__device__ __forceinline__ float bf2f(unsigned s) {
    return __uint_as_float(s << 16);
}
// packed f32x2 -> bf16x2 (RNE)
__device__ __forceinline__ unsigned pk2(float lo, float hi) {
    float2 t; t.x = lo; t.y = hi;
    __hip_bfloat162 hh = __float22bfloat162_rn(t);
    return *reinterpret_cast<unsigned*>(&hh);
}

// ---------------------------------------------------------------------------
// Prep: fold BN1/BN2 into attention weights, transpose all weights to bf16
// ---------------------------------------------------------------------------
__global__ void prep_kernel(const float* __restrict__ w3,
                            const float* __restrict__ g1, const float* __restrict__ be1,
                            const float* __restrict__ m1, const float* __restrict__ v1,
                            const float* __restrict__ wa1, const float* __restrict__ ba1,
                            const float* __restrict__ g2, const float* __restrict__ be2,
                            const float* __restrict__ m2, const float* __restrict__ v2,
                            const float* __restrict__ wa2, const float* __restrict__ ba2,
                            unsigned short* __restrict__ w3T,
                            unsigned short* __restrict__ wa1T,
                            unsigned short* __restrict__ wa2T,
                            float* __restrict__ b_a1p, float* __restrict__ b_a2p)
{
    const int blk = blockIdx.x;
    const int tid = threadIdx.x;
    if (blk < 64) {
        #pragma unroll
        for (int i = 0; i < 4; ++i) {
            int f = blk * 4 + i;
            w3T[f * 256 + tid] = f2bf(w3[tid * 256 + f]);
        }
    } else if (blk < 96) {
        int a = blk - 64;
        int c = tid;
        float s1 = rsqrtf(v1[c] + EPS) * g1[c];
        float wv = wa1[c * 32 + a];
        wa1T[a * 256 + c] = f2bf(wv * s1);
        float part = (be1[c] - m1[c] * s1) * wv;
        __shared__ float red[4];
        #pragma unroll
        for (int off = 32; off > 0; off >>= 1) part += __shfl_down(part, off);
        if ((tid & 63) == 0) red[tid >> 6] = part;
        __syncthreads();
        if (tid == 0) b_a1p[a] = ba1[a] + red[0] + red[1] + red[2] + red[3];
    } else {
        int f = tid;
        float acc = ba2[f];
        #pragma unroll
        for (int a = 0; a < 32; ++a) {
            float s2 = rsqrtf(v2[a] + EPS) * g2[a];
            float wv = wa2[a * 256 + f];
            wa2T[f * 32 + a] = f2bf(wv * s2);
            acc += (be2[a] - m2[a] * s2) * wv;
        }
        b_a2p[f] = acc;
    }
}

// ---------------------------------------------------------------------------
// Kernel A: a1 = relu(x_bn @ wa1')  [65536 px x 32], bf16 out to workspace.
// Block = one image row, 4 waves x 16 px. Tiny LDS (5 KB bounce), no barrier.
// a1g layout: [row 0..1023][px 0..63][a 0..31] bf16 (4 KB per row).
// ---------------------------------------------------------------------------
__global__ __launch_bounds__(256, 8)
void attn1_kernel(const float* __restrict__ x,
                  const unsigned short* __restrict__ wa1T,
                  const float* __restrict__ b_a1p,
                  unsigned short* __restrict__ a1g)
{
    __shared__ __align__(16) unsigned char lds[5120];

    const int tid = threadIdx.x;
    const int bid = blockIdx.x;
    const int row = (bid & 7) * 128 + (bid >> 3);   // XCD swizzle

    const int wv   = tid >> 6;
    const int lane = tid & 63;
    const int cl   = lane & 15;
    const int lkg  = lane >> 4;

    const float* xr = x + ((size_t)row * 64 + wv * 16 + cl) * 256;

    f32x4 acc1[2];
    acc1[0] = (f32x4){0,0,0,0};
    acc1[1] = (f32x4){0,0,0,0};
    #pragma unroll
    for (int kk = 0; kk < 8; ++kk) {
        f4 u0 = *(const f4*)(xr + kk * 32 + lkg * 8);
        f4 u1 = *(const f4*)(xr + kk * 32 + lkg * 8 + 4);
        unsigned apv[4];
        apv[0] = pk2(u0.x, u0.y); apv[1] = pk2(u0.z, u0.w);
        apv[2] = pk2(u1.x, u1.y); apv[3] = pk2(u1.z, u1.w);
        short8 afr = *reinterpret_cast<short8*>(apv);
        #pragma unroll
        for (int t = 0; t < 2; ++t) {
            short8 bfr = *(const short8*)(wa1T + ((t * 16 + cl) * 256 + kk * 32 + lkg * 8));
            acc1[t] = __builtin_amdgcn_mfma_f32_16x16x32_bf16(afr, bfr, acc1[t], 0, 0, 0);
        }
    }
    // C layout: row m = lkg*4+r (px = wv*16+m), col a = t*16+cl.
    // bounce via per-wave LDS (pitch 80 B), then one coalesced 16 B store/lane
    const unsigned a1base = (unsigned)wv * 1280u;
    #pragma unroll
    for (int t = 0; t < 2; ++t) {
        int a = t * 16 + cl;
        float bb = b_a1p[a];
        #pragma unroll
        for (int r = 0; r < 4; ++r) {
            float vv = acc1[t][r] + bb;
            vv = vv > 0.f ? vv : 0.f;
            int m = lkg * 4 + r;
            *(unsigned short*)(lds + a1base + m * 80 + a * 2) = f2bf(vv);
        }
    }
    asm volatile("s_waitcnt lgkmcnt(0)" ::: "memory");
    __builtin_amdgcn_sched_barrier(0);
    uint4 v = *(const uint4*)(lds + a1base + (lane >> 2) * 80 + (lane & 3) * 16);
    *(uint4*)(a1g + (size_t)row * 2048 + wv * 512 + lane * 8) = v;
}

// ---------------------------------------------------------------------------
// Kernel B: box-sum staging + GEMM2(a1 ws) + softmax + main GEMM + multiply.
// Block = HALF an image row (32 px), 8 waves; 2048 blocks = 256 CU x 4
// resident x 2 exact rounds (no partial tail). Per wave: 32-f slice x 32 px.
// Phase 1 (ILP-overlapped, independent):
//   - stage own 4-px strip (+2 halo): rolling 3-reg window -> xs bf16 LDS
//   - GEMM2 slice: e[32f][32px] (4 MFMA), exp (no max-sub), psum -> LDS
// ONE barrier. Phase 2: main GEMM f-split (ds_read+MFMA, w3T from L2),
// epilogue o = e*invS*(s+cnt*b3), e lane-local (C-layouts match).
// LDS 17408 B: xs[0,16384) [32px][256c] bf16 XOR-swizzled;
//              psum[16384,17408) = [8 wv][32 px] f32.
// launch_bounds(512,8): 4 blocks/CU, VGPR cap 64 (R7 measured 40).
// ---------------------------------------------------------------------------
__global__ __launch_bounds__(512, 8)
void fused2_kernel(const float* __restrict__ x,
                   const unsigned short* __restrict__ a1g,
                   const float* __restrict__ b3,
                   const unsigned short* __restrict__ w3T,
                   const unsigned short* __restrict__ wa2T,
                   const float* __restrict__ b_a2p,
                   float* __restrict__ out)
{
    __shared__ __align__(16) unsigned char lds[17408];

    const int tid = threadIdx.x;
    const int bid = blockIdx.x;
    const int g   = (bid & 7) * 256 + (bid >> 3);   // XCD swizzle (2048%8==0)
    const int row = g >> 1;
    const int ph  = g & 1;                          // px half: 0 -> 0..31, 1 -> 32..63
    const int h   = row & 63;

    const int wv   = tid >> 6;
    const int lane = tid & 63;
    const int cl   = lane & 15;
    const int lkg  = lane >> 4;
    const int F0   = wv * 32;

    const size_t rowb = (size_t)row * 64 * 256;
    const float* xrow = x + rowb;
    const bool hm = (h > 0), hp = (h < 63);
    const f4* pc = (const f4*)xrow;
    const f4* pm = (const f4*)(xrow - 16384);
    const f4* pp = (const f4*)(xrow + 16384);
    const f4 z4 = {0.f, 0.f, 0.f, 0.f};

    // ------- phase 1a: stage own 4-px strip (rolling window) -> xs ---------
    {
        f4 w0 = z4, w1 = z4, w2 = z4;
        #pragma unroll
        for (int r = 0; r < 6; ++r) {
            int gl  = wv * 4 - 1 + r;              // local px being loaded
            int gpx = ph * 32 + gl;                // global px in the row
            f4 vr = z4;
            if (gpx >= 0 && gpx < 64) {
                int idx = gpx * 64 + lane;
                f4 a0 = pc[idx];
                f4 am = hm ? pm[idx] : z4;
                f4 ap = hp ? pp[idx] : z4;
                vr = a0 + am + ap;
            }
            w2 = vr;
            if (r >= 2) {
                f4 s = w0 + w1 + w2;
                int j = wv * 4 + r - 2;            // local row 0..31
                unsigned addr = (unsigned)j * 512u +
                                (((unsigned)lane * 8u) ^ (((unsigned)j & 7u) << 4));
                uint2 pk;
                pk.x = pk2(s.x, s.y);
                pk.y = pk2(s.z, s.w);
                *(uint2*)(lds + addr) = pk;
            }
            w0 = w1; w1 = w2;
        }
    }

    // ------- phase 1b: GEMM2 slice + exp + psum ----------------------------
    // D[f = F0+ft*16+lkg*4+r][px_local = pt*16+cl]  (== main GEMM C-layout)
    uint2 ep[2][2];                    // e packed bf16
    {
        const unsigned short* a1row = a1g + (size_t)row * 2048;
        f32x4 a2[2][2];
        #pragma unroll
        for (int ft = 0; ft < 2; ++ft) {
            short8 wfr = *(const short8*)(wa2T + ((F0 + ft * 16 + cl) * 32 + lkg * 8));
            #pragma unroll
            for (int pt = 0; pt < 2; ++pt) {
                short8 bfr = *(const short8*)(a1row + ((ph * 32 + pt * 16 + cl) * 32 + lkg * 8));
                f32x4 z = {0,0,0,0};
                a2[ft][pt] = __builtin_amdgcn_mfma_f32_16x16x32_bf16(wfr, bfr, z, 0, 0, 0);
            }
        }
        f4 bb[2];
        #pragma unroll
        for (int ft = 0; ft < 2; ++ft)
            bb[ft] = *(const f4*)(b_a2p + F0 + ft * 16 + lkg * 4);

        float ps[2];
        #pragma unroll
        for (int pt = 0; pt < 2; ++pt) {
            float e[2][4];
            #pragma unroll
            for (int ft = 0; ft < 2; ++ft) {
                #pragma unroll
                for (int r = 0; r < 4; ++r) {
                    float vv = a2[ft][pt][r] + bb[ft][r];
                    vv = vv > 0.f ? vv : 0.f;
                    e[ft][r] = __expf(vv);
                }
                ep[ft][pt].x = pk2(e[ft][0], e[ft][1]);
                ep[ft][pt].y = pk2(e[ft][2], e[ft][3]);
            }
            float s = ((e[0][0] + e[0][1]) + (e[0][2] + e[0][3]))
                    + ((e[1][0] + e[1][1]) + (e[1][2] + e[1][3]));
            s += __shfl_xor(s, 16);
            s += __shfl_xor(s, 32);
            ps[pt] = s;               // replicated across lkg
        }
        // one writer per local px: lanes with lkg<2 write px = lkg*16+cl = lane
        if (lkg < 2) {
            float wsum = lkg ? ps[1] : ps[0];
            *(float*)(lds + 16384 + wv * 128 + lane * 4) = wsum;
        }
    }

    __syncthreads();   // xs + psum published

    // ------- phase 2: main GEMM (f-split, 32f x 32px) ----------------------
    f32x4 acc[2][2];
    #pragma unroll
    for (int ft = 0; ft < 2; ++ft)
        #pragma unroll
        for (int pt = 0; pt < 2; ++pt) acc[ft][pt] = (f32x4){0,0,0,0};

    #pragma unroll
    for (int kk = 0; kk < 8; ++kk) {
        short8 afr[2];
        #pragma unroll
        for (int ft = 0; ft < 2; ++ft)
            afr[ft] = *(const short8*)(w3T + ((F0 + ft * 16 + cl) * 256 + kk * 32 + lkg * 8));
        short8 xfr[2];
        #pragma unroll
        for (int pt = 0; pt < 2; ++pt) {
            unsigned px = (unsigned)(pt * 16 + cl);
            unsigned ad = px * 512u +
                          (((unsigned)(kk * 64 + lkg * 16)) ^ (((unsigned)px & 7u) << 4));
            xfr[pt] = *(const short8*)(lds + ad);
        }
        #pragma unroll
        for (int ft = 0; ft < 2; ++ft)
            #pragma unroll
            for (int pt = 0; pt < 2; ++pt)
                acc[ft][pt] = __builtin_amdgcn_mfma_f32_16x16x32_bf16(afr[ft], xfr[pt], acc[ft][pt], 0, 0, 0);
    }

    // ------- epilogue: o = e * invS * (s + cnt*b3) -------------------------
    const int rh = (h == 0 || h == 63) ? 2 : 3;
    f4 b3v[2];
    #pragma unroll
    for (int ft = 0; ft < 2; ++ft)
        b3v[ft] = *(const f4*)(b3 + F0 + ft * 16 + lkg * 4);
    #pragma unroll
    for (int pt = 0; pt < 2; ++pt) {
        int pxl = pt * 16 + cl;
        int gpx = ph * 32 + pxl;
        float den = 0.f;
        #pragma unroll
        for (int w = 0; w < 8; ++w)
            den += *(const float*)(lds + 16384 + w * 128 + pxl * 4);
        float is = 1.f / den;
        float cnt = (float)(rh * ((gpx == 0 || gpx == 63) ? 2 : 3));
        #pragma unroll
        for (int ft = 0; ft < 2; ++ft) {
            int f0 = F0 + ft * 16 + lkg * 4;
            uint2 ev = ep[ft][pt];
            f4 o;
            o.x = bf2f(ev.x & 0xffffu) * is * (acc[ft][pt][0] + cnt * b3v[ft].x);
            o.y = bf2f(ev.x >> 16)     * is * (acc[ft][pt][1] + cnt * b3v[ft].y);
            o.z = bf2f(ev.y & 0xffffu) * is * (acc[ft][pt][2] + cnt * b3v[ft].z);
            o.w = bf2f(ev.y >> 16)     * is * (acc[ft][pt][3] + cnt * b3v[ft].w);
            *(f4*)(out + rowb + (size_t)gpx * 256 + f0) = o;
        }
    }
}

extern "C" void kernel_launch(void* const* d_in, const int* in_sizes, int n_in,
                              void* d_out, int out_size, void* d_ws, size_t ws_size,
                              hipStream_t stream)
{
    const float* x   = (const float*)d_in[0];
    const float* w3  = (const float*)d_in[1];
    const float* b3  = (const float*)d_in[2];
    const float* g1  = (const float*)d_in[3];
    const float* be1 = (const float*)d_in[4];
    const float* m1  = (const float*)d_in[5];
    const float* v1  = (const float*)d_in[6];
    const float* wa1 = (const float*)d_in[7];
    const float* ba1 = (const float*)d_in[8];
    const float* g2  = (const float*)d_in[9];
    const float* be2 = (const float*)d_in[10];
    const float* m2  = (const float*)d_in[11];
    const float* v2  = (const float*)d_in[12];
    const float* wa2 = (const float*)d_in[13];
    const float* ba2 = (const float*)d_in[14];

    unsigned char* ws = (unsigned char*)d_ws;
    unsigned short* w3T   = (unsigned short*)(ws);
    unsigned short* wa1T  = (unsigned short*)(ws + 131072);
    unsigned short* wa2T  = (unsigned short*)(ws + 147456);
    float*          b_a1p = (float*)(ws + 163840);
    float*          b_a2p = (float*)(ws + 163968);
    unsigned short* a1g   = (unsigned short*)(ws + 196608);   // 4 MB

    hipLaunchKernelGGL(prep_kernel, dim3(97), dim3(256), 0, stream,
                       w3, g1, be1, m1, v1, wa1, ba1, g2, be2, m2, v2, wa2, ba2,
                       w3T, wa1T, wa2T, b_a1p, b_a2p);
    hipLaunchKernelGGL(attn1_kernel, dim3(1024), dim3(256), 0, stream,
                       x, wa1T, b_a1p, a1g);
    hipLaunchKernelGGL(fused2_kernel, dim3(2048), dim3(512), 0, stream,
                       x, a1g, b3, w3T, wa2T, b_a2p, (float*)d_out);
}

// Round 9
// 72.874 us; speedup vs baseline: 1.0911x; 1.0911x over previous
//
#include <hip/hip_runtime.h>
#include <hip/hip_bf16.h>

#define EPS 1e-3f

typedef float f32x4 __attribute__((ext_vector_type(4)));
typedef float f4    __attribute__((ext_vector_type(4)));
typedef short short8 __attribute__((ext_vector_type(8)));

__device__ __forceinline__ unsigned short f2bf(float f) {
    unsigned u = __float_as_uint(f);
    u += 0x7FFFu + ((u >> 16) & 1u);   // round-to-nearest-even
    return (unsigned short)(u >> 16);
}
__device__ __forceinline__ float bf2f(unsigned s) {
    return __uint_as_float(s << 16);
}
// packed f32x2 -> bf16x2 (RNE)
__device__ __forceinline__ unsigned pk2(float lo, float hi) {
    float2 t; t.x = lo; t.y = hi;
    __hip_bfloat162 hh = __float22bfloat162_rn(t);
    return *reinterpret_cast<unsigned*>(&hh);
}

// ---------------------------------------------------------------------------
// Prep: fold BN1/BN2 into attention weights, transpose all weights to bf16
// ---------------------------------------------------------------------------
__global__ void prep_kernel(const float* __restrict__ w3,
                            const float* __restrict__ g1, const float* __restrict__ be1,
                            const float* __restrict__ m1, const float* __restrict__ v1,
                            const float* __restrict__ wa1, const float* __restrict__ ba1,
                            const float* __restrict__ g2, const float* __restrict__ be2,
                            const float* __restrict__ m2, const float* __restrict__ v2,
                            const float* __restrict__ wa2, const float* __restrict__ ba2,
                            unsigned short* __restrict__ w3T,
                            unsigned short* __restrict__ wa1T,
                            unsigned short* __restrict__ wa2T,
                            float* __restrict__ b_a1p, float* __restrict__ b_a2p)
{
    const int blk = blockIdx.x;
    const int tid = threadIdx.x;
    if (blk < 64) {
        #pragma unroll
        for (int i = 0; i < 4; ++i) {
            int f = blk * 4 + i;
            w3T[f * 256 + tid] = f2bf(w3[tid * 256 + f]);
        }
    } else if (blk < 96) {
        int a = blk - 64;
        int c = tid;
        float s1 = rsqrtf(v1[c] + EPS) * g1[c];
        float wv = wa1[c * 32 + a];
        wa1T[a * 256 + c] = f2bf(wv * s1);
        float part = (be1[c] - m1[c] * s1) * wv;
        __shared__ float red[4];
        #pragma unroll
        for (int off = 32; off > 0; off >>= 1) part += __shfl_down(part, off);
        if ((tid & 63) == 0) red[tid >> 6] = part;
        __syncthreads();
        if (tid == 0) b_a1p[a] = ba1[a] + red[0] + red[1] + red[2] + red[3];
    } else {
        int f = tid;
        float acc = ba2[f];
        #pragma unroll
        for (int a = 0; a < 32; ++a) {
            float s2 = rsqrtf(v2[a] + EPS) * g2[a];
            float wv = wa2[a * 256 + f];
            wa2T[f * 32 + a] = f2bf(wv * s2);
            acc += (be2[a] - m2[a] * s2) * wv;
        }
        b_a2p[f] = acc;
    }
}

// ---------------------------------------------------------------------------
// Front kernel: per image row, (1) vsum[h] = x[h-1]+x[h]+x[h+1] -> bf16 ws,
// (2) a1 = relu(x_bn @ wa1') -> bf16 ws.  Block = one row, 4 waves x 16 px.
// x staged bf16 in LDS during the vsum pass, so GEMM1 A-frags come from LDS.
// LDS 37888: xbf[0,32768) swizzled; bounce[32768,37888) pitch-80 per wave.
// vsum layout: [row][px 0..63][c 0..255] bf16 (32 KB/row).
// ---------------------------------------------------------------------------
__global__ __launch_bounds__(256, 8)
void front_kernel(const float* __restrict__ x,
                  const unsigned short* __restrict__ wa1T,
                  const float* __restrict__ b_a1p,
                  unsigned short* __restrict__ vsum_g,
                  unsigned short* __restrict__ a1g)
{
    __shared__ __align__(16) unsigned char lds[37888];

    const int tid = threadIdx.x;
    const int bid = blockIdx.x;
    const int row = (bid & 7) * 128 + (bid >> 3);   // XCD swizzle
    const int h   = row & 63;

    const int wv   = tid >> 6;
    const int lane = tid & 63;
    const int cl   = lane & 15;
    const int lkg  = lane >> 4;

    const float* xrow = x + (size_t)row * 16384;
    const bool hm = (h > 0), hp = (h < 63);
    const f4* pc = (const f4*)xrow;
    const f4* pm = (const f4*)(xrow - 16384);
    const f4* pp = (const f4*)(xrow + 16384);
    const f4 z4 = {0.f, 0.f, 0.f, 0.f};
    unsigned short* vrow = vsum_g + (size_t)row * 16384;

    // ------- pass 1: vertical 3-row sum -> vsum ws; center row -> xbf LDS --
    #pragma unroll
    for (int j = 0; j < 16; ++j) {
        int v  = tid + j * 256;        // f4 index 0..4095
        int px = v >> 6;
        int c4 = v & 63;
        f4 a0 = pc[v];
        f4 am = hm ? pm[v] : z4;
        f4 ap = hp ? pp[v] : z4;
        f4 s = a0 + am + ap;
        uint2 pv;
        pv.x = pk2(s.x, s.y);
        pv.y = pk2(s.z, s.w);
        *(uint2*)(vrow + (size_t)v * 4) = pv;     // coalesced bf16 store
        uint2 pb;
        pb.x = pk2(a0.x, a0.y);
        pb.y = pk2(a0.z, a0.w);
        unsigned ad = (unsigned)px * 512u +
                      (((unsigned)c4 * 8u) ^ (((unsigned)px & 7u) << 4));
        *(uint2*)(lds + ad) = pb;
    }
    __syncthreads();

    // ------- pass 2: GEMM1 (A from LDS), bounce, a1g store -----------------
    const int arow = wv * 16 + cl;
    f32x4 acc1[2];
    acc1[0] = (f32x4){0,0,0,0};
    acc1[1] = (f32x4){0,0,0,0};
    #pragma unroll
    for (int kk = 0; kk < 8; ++kk) {
        unsigned ad = (unsigned)arow * 512u +
                      (((unsigned)(kk * 64 + lkg * 16)) ^ (((unsigned)arow & 7u) << 4));
        short8 afr = *(const short8*)(lds + ad);
        #pragma unroll
        for (int t = 0; t < 2; ++t) {
            short8 bfr = *(const short8*)(wa1T + ((t * 16 + cl) * 256 + kk * 32 + lkg * 8));
            acc1[t] = __builtin_amdgcn_mfma_f32_16x16x32_bf16(afr, bfr, acc1[t], 0, 0, 0);
        }
    }
    const unsigned a1base = 32768u + (unsigned)wv * 1280u;
    #pragma unroll
    for (int t = 0; t < 2; ++t) {
        int a = t * 16 + cl;
        float bb = b_a1p[a];
        #pragma unroll
        for (int r = 0; r < 4; ++r) {
            float vv = acc1[t][r] + bb;
            vv = vv > 0.f ? vv : 0.f;
            int m = lkg * 4 + r;
            *(unsigned short*)(lds + a1base + m * 80 + a * 2) = f2bf(vv);
        }
    }
    asm volatile("s_waitcnt lgkmcnt(0)" ::: "memory");
    __builtin_amdgcn_sched_barrier(0);
    uint4 v = *(const uint4*)(lds + a1base + (lane >> 2) * 80 + (lane & 3) * 16);
    *(uint4*)(a1g + (size_t)row * 2048 + wv * 512 + lane * 8) = v;
}

// ---------------------------------------------------------------------------
// Kernel B: horizontal fold (vsum ws, L3-hot) + GEMM2(a1 ws) + softmax +
// main GEMM + multiply. Block = one image row, 8 waves; 1024 blocks =
// 256 CU x 4 resident = ONE round. Per wave: 32-f slice x 64 px.
// Phase 1 (independent, ILP-overlapped):
//   - fold: xs[px][c] = vsum[px-1]+vsum[px]+vsum[px+1], 12x16B bf16 loads
//   - GEMM2 slice: e[32f][64px] (8 MFMA), exp (no max-sub), psum -> LDS
// ONE barrier. Phase 2: main GEMM f-split (ds_read+MFMA, w3T L2),
// epilogue o = e*invS*(s+cnt*b3), e lane-local (C-layouts match).
// LDS 34816: xs[0,32768) swizzled; psum[32768,34816) = [8 wv][64 px] f32.
// launch_bounds(512,8): VGPR<=64 -> 4 blocks/CU guaranteed by LDS+threads.
// ---------------------------------------------------------------------------
__global__ __launch_bounds__(512, 8)
void fused2_kernel(const unsigned short* __restrict__ vsum_g,
                   const unsigned short* __restrict__ a1g,
                   const float* __restrict__ b3,
                   const unsigned short* __restrict__ w3T,
                   const unsigned short* __restrict__ wa2T,
                   const float* __restrict__ b_a2p,
                   float* __restrict__ out)
{
    __shared__ __align__(16) unsigned char lds[34816];

    const int tid = threadIdx.x;
    const int bid = blockIdx.x;
    const int row = (bid & 7) * 128 + (bid >> 3);   // XCD swizzle
    const int h   = row & 63;

    const int wv   = tid >> 6;
    const int lane = tid & 63;
    const int cl   = lane & 15;
    const int lkg  = lane >> 4;
    const int F0   = wv * 32;

    // ------- phase 1a: horizontal 3-tap fold vsum -> xs --------------------
    {
        const unsigned char* vrow = (const unsigned char*)(vsum_g + (size_t)row * 16384);
        #pragma unroll
        for (int i = 0; i < 4; ++i) {
            int a  = tid + i * 512;        // assignment 0..2047
            int px = a >> 5;
            int cb = (a & 31) * 16;        // byte offset within px row
            float s0=0.f,s1=0.f,s2=0.f,s3=0.f,s4=0.f,s5=0.f,s6=0.f,s7=0.f;
            #pragma unroll
            for (int d = -1; d <= 1; ++d) {
                int p = px + d;
                if (p >= 0 && p < 64) {
                    uint4 q = *(const uint4*)(vrow + p * 512 + cb);
                    s0 += bf2f(q.x & 0xffffu); s1 += bf2f(q.x >> 16);
                    s2 += bf2f(q.y & 0xffffu); s3 += bf2f(q.y >> 16);
                    s4 += bf2f(q.z & 0xffffu); s5 += bf2f(q.z >> 16);
                    s6 += bf2f(q.w & 0xffffu); s7 += bf2f(q.w >> 16);
                }
            }
            uint4 o;
            o.x = pk2(s0, s1); o.y = pk2(s2, s3);
            o.z = pk2(s4, s5); o.w = pk2(s6, s7);
            unsigned ad = (unsigned)px * 512u +
                          (((unsigned)cb) ^ (((unsigned)px & 7u) << 4));
            *(uint4*)(lds + ad) = o;
        }
    }

    // ------- phase 1b: GEMM2 slice + exp + psum ----------------------------
    // D[f = F0+ft*16+lkg*4+r][px = pt*16+cl]  (== main GEMM C-layout)
    uint2 ep[2][4];                    // e packed bf16
    {
        const unsigned short* a1row = a1g + (size_t)row * 2048;
        f32x4 a2[2][4];
        #pragma unroll
        for (int ft = 0; ft < 2; ++ft) {
            short8 wfr = *(const short8*)(wa2T + ((F0 + ft * 16 + cl) * 32 + lkg * 8));
            #pragma unroll
            for (int pt = 0; pt < 4; ++pt) {
                short8 bfr = *(const short8*)(a1row + ((pt * 16 + cl) * 32 + lkg * 8));
                f32x4 z = {0,0,0,0};
                a2[ft][pt] = __builtin_amdgcn_mfma_f32_16x16x32_bf16(wfr, bfr, z, 0, 0, 0);
            }
        }
        f4 bb[2];
        #pragma unroll
        for (int ft = 0; ft < 2; ++ft)
            bb[ft] = *(const f4*)(b_a2p + F0 + ft * 16 + lkg * 4);

        float ps[4];
        #pragma unroll
        for (int pt = 0; pt < 4; ++pt) {
            float e[2][4];
            #pragma unroll
            for (int ft = 0; ft < 2; ++ft) {
                #pragma unroll
                for (int r = 0; r < 4; ++r) {
                    float vv = a2[ft][pt][r] + bb[ft][r];
                    vv = vv > 0.f ? vv : 0.f;
                    e[ft][r] = __expf(vv);
                }
                ep[ft][pt].x = pk2(e[ft][0], e[ft][1]);
                ep[ft][pt].y = pk2(e[ft][2], e[ft][3]);
            }
            float s = ((e[0][0] + e[0][1]) + (e[0][2] + e[0][3]))
                    + ((e[1][0] + e[1][1]) + (e[1][2] + e[1][3]));
            s += __shfl_xor(s, 16);
            s += __shfl_xor(s, 32);
            ps[pt] = s;               // replicated across lkg
        }
        // one writer per px: lane with lkg==pt writes px = lkg*16+cl = lane
        float wsum = (lkg == 0) ? ps[0] : (lkg == 1) ? ps[1]
                   : (lkg == 2) ? ps[2] : ps[3];
        *(float*)(lds + 32768 + wv * 256 + lane * 4) = wsum;
    }

    __syncthreads();   // xs + psum published

    // ------- phase 2: main GEMM (f-split, 32f x 64px) ----------------------
    f32x4 acc[2][4];
    #pragma unroll
    for (int ft = 0; ft < 2; ++ft)
        #pragma unroll
        for (int pt = 0; pt < 4; ++pt) acc[ft][pt] = (f32x4){0,0,0,0};

    #pragma unroll
    for (int kk = 0; kk < 8; ++kk) {
        short8 afr[2];
        #pragma unroll
        for (int ft = 0; ft < 2; ++ft)
            afr[ft] = *(const short8*)(w3T + ((F0 + ft * 16 + cl) * 256 + kk * 32 + lkg * 8));
        short8 xfr[4];
        #pragma unroll
        for (int pt = 0; pt < 4; ++pt) {
            unsigned px = (unsigned)(pt * 16 + cl);
            unsigned ad = px * 512u +
                          (((unsigned)(kk * 64 + lkg * 16)) ^ (((unsigned)px & 7u) << 4));
            xfr[pt] = *(const short8*)(lds + ad);
        }
        #pragma unroll
        for (int ft = 0; ft < 2; ++ft)
            #pragma unroll
            for (int pt = 0; pt < 4; ++pt)
                acc[ft][pt] = __builtin_amdgcn_mfma_f32_16x16x32_bf16(afr[ft], xfr[pt], acc[ft][pt], 0, 0, 0);
    }

    // ------- epilogue: o = e * invS * (s + cnt*b3) -------------------------
    const int rh = (h == 0 || h == 63) ? 2 : 3;
    const size_t rowb = (size_t)row * 16384;
    f4 b3v[2];
    #pragma unroll
    for (int ft = 0; ft < 2; ++ft)
        b3v[ft] = *(const f4*)(b3 + F0 + ft * 16 + lkg * 4);
    #pragma unroll
    for (int pt = 0; pt < 4; ++pt) {
        int px = pt * 16 + cl;
        float den = 0.f;
        #pragma unroll
        for (int w = 0; w < 8; ++w)
            den += *(const float*)(lds + 32768 + w * 256 + px * 4);
        float is = 1.f / den;
        float cnt = (float)(rh * ((px == 0 || px == 63) ? 2 : 3));
        #pragma unroll
        for (int ft = 0; ft < 2; ++ft) {
            int f0 = F0 + ft * 16 + lkg * 4;
            uint2 ev = ep[ft][pt];
            f4 o;
            o.x = bf2f(ev.x & 0xffffu) * is * (acc[ft][pt][0] + cnt * b3v[ft].x);
            o.y = bf2f(ev.x >> 16)     * is * (acc[ft][pt][1] + cnt * b3v[ft].y);
            o.z = bf2f(ev.y & 0xffffu) * is * (acc[ft][pt][2] + cnt * b3v[ft].z);
            o.w = bf2f(ev.y >> 16)     * is * (acc[ft][pt][3] + cnt * b3v[ft].w);
            *(f4*)(out + rowb + (size_t)px * 256 + f0) = o;
        }
    }
}

extern "C" void kernel_launch(void* const* d_in, const int* in_sizes, int n_in,
                              void* d_out, int out_size, void* d_ws, size_t ws_size,
                              hipStream_t stream)
{
    const float* x   = (const float*)d_in[0];
    const float* w3  = (const float*)d_in[1];
    const float* b3  = (const float*)d_in[2];
    const float* g1  = (const float*)d_in[3];
    const float* be1 = (const float*)d_in[4];
    const float* m1  = (const float*)d_in[5];
    const float* v1  = (const float*)d_in[6];
    const float* wa1 = (const float*)d_in[7];
    const float* ba1 = (const float*)d_in[8];
    const float* g2  = (const float*)d_in[9];
    const float* be2 = (const float*)d_in[10];
    const float* m2  = (const float*)d_in[11];
    const float* v2  = (const float*)d_in[12];
    const float* wa2 = (const float*)d_in[13];
    const float* ba2 = (const float*)d_in[14];

    unsigned char* ws = (unsigned char*)d_ws;
    unsigned short* w3T   = (unsigned short*)(ws);
    unsigned short* wa1T  = (unsigned short*)(ws + 131072);
    unsigned short* wa2T  = (unsigned short*)(ws + 147456);
    float*          b_a1p = (float*)(ws + 163840);
    float*          b_a2p = (float*)(ws + 163968);
    unsigned short* a1g   = (unsigned short*)(ws + 196608);            // 4 MB
    unsigned short* vsum_g= (unsigned short*)(ws + 196608 + 4194304);  // 32 MB

    hipLaunchKernelGGL(prep_kernel, dim3(97), dim3(256), 0, stream,
                       w3, g1, be1, m1, v1, wa1, ba1, g2, be2, m2, v2, wa2, ba2,
                       w3T, wa1T, wa2T, b_a1p, b_a2p);
    hipLaunchKernelGGL(front_kernel, dim3(1024), dim3(256), 0, stream,
                       x, wa1T, b_a1p, vsum_g, a1g);
    hipLaunchKernelGGL(fused2_kernel, dim3(1024), dim3(512), 0, stream,
                       vsum_g, a1g, b3, w3T, wa2T, b_a2p, (float*)d_out);
}

// Round 10
// 68.716 us; speedup vs baseline: 1.1572x; 1.0605x over previous
//
#include <hip/hip_runtime.h>
#include <hip/hip_bf16.h>

#define EPS 1e-3f

typedef float f32x4 __attribute__((ext_vector_type(4)));
typedef float f4    __attribute__((ext_vector_type(4)));
typedef short short8 __attribute__((ext_vector_type(8)));

__device__ __forceinline__ unsigned short f2bf(float f) {
    unsigned u = __float_as_uint(f);
    u += 0x7FFFu + ((u >> 16) & 1u);   // round-to-nearest-even
    return (unsigned short)(u >> 16);
}
__device__ __forceinline__ float bf2f(unsigned s) {
    return __uint_as_float(s << 16);
}
// packed f32x2 -> bf16x2 (RNE)
__device__ __forceinline__ unsigned pk2(float lo, float hi) {
    float2 t; t.x = lo; t.y = hi;
    __hip_bfloat162 hh = __float22bfloat162_rn(t);
    return *reinterpret_cast<unsigned*>(&hh);
}

// ---------------------------------------------------------------------------
// Prep: fold BN1/BN2 into attention weights, transpose all weights to bf16
// ---------------------------------------------------------------------------
__global__ void prep_kernel(const float* __restrict__ w3,
                            const float* __restrict__ g1, const float* __restrict__ be1,
                            const float* __restrict__ m1, const float* __restrict__ v1,
                            const float* __restrict__ wa1, const float* __restrict__ ba1,
                            const float* __restrict__ g2, const float* __restrict__ be2,
                            const float* __restrict__ m2, const float* __restrict__ v2,
                            const float* __restrict__ wa2, const float* __restrict__ ba2,
                            unsigned short* __restrict__ w3T,
                            unsigned short* __restrict__ wa1T,
                            unsigned short* __restrict__ wa2T,
                            float* __restrict__ b_a1p, float* __restrict__ b_a2p)
{
    const int blk = blockIdx.x;
    const int tid = threadIdx.x;
    if (blk < 64) {
        #pragma unroll
        for (int i = 0; i < 4; ++i) {
            int f = blk * 4 + i;
            w3T[f * 256 + tid] = f2bf(w3[tid * 256 + f]);
        }
    } else if (blk < 96) {
        int a = blk - 64;
        int c = tid;
        float s1 = rsqrtf(v1[c] + EPS) * g1[c];
        float wv = wa1[c * 32 + a];
        wa1T[a * 256 + c] = f2bf(wv * s1);
        float part = (be1[c] - m1[c] * s1) * wv;
        __shared__ float red[4];
        #pragma unroll
        for (int off = 32; off > 0; off >>= 1) part += __shfl_down(part, off);
        if ((tid & 63) == 0) red[tid >> 6] = part;
        __syncthreads();
        if (tid == 0) b_a1p[a] = ba1[a] + red[0] + red[1] + red[2] + red[3];
    } else {
        int f = tid;
        float acc = ba2[f];
        #pragma unroll
        for (int a = 0; a < 32; ++a) {
            float s2 = rsqrtf(v2[a] + EPS) * g2[a];
            float wv = wa2[a * 256 + f];
            wa2T[f * 32 + a] = f2bf(wv * s2);
            acc += (be2[a] - m2[a] * s2) * wv;
        }
        b_a2p[f] = acc;
    }
}

// ---------------------------------------------------------------------------
// Kernel A: a1 = relu(x_bn @ wa1')  [65536 px x 32], bf16 out to workspace.
// Block = one image row, 4 waves x 16 px. Tiny LDS (5 KB bounce), no barrier.
// a1g layout: [row 0..1023][px 0..63][a 0..31] bf16 (4 KB per row).
// ---------------------------------------------------------------------------
__global__ __launch_bounds__(256, 8)
void attn1_kernel(const float* __restrict__ x,
                  const unsigned short* __restrict__ wa1T,
                  const float* __restrict__ b_a1p,
                  unsigned short* __restrict__ a1g)
{
    __shared__ __align__(16) unsigned char lds[5120];

    const int tid = threadIdx.x;
    const int bid = blockIdx.x;
    const int row = (bid & 7) * 128 + (bid >> 3);   // XCD swizzle

    const int wv   = tid >> 6;
    const int lane = tid & 63;
    const int cl   = lane & 15;
    const int lkg  = lane >> 4;

    const float* xr = x + ((size_t)row * 64 + wv * 16 + cl) * 256;

    f32x4 acc1[2];
    acc1[0] = (f32x4){0,0,0,0};
    acc1[1] = (f32x4){0,0,0,0};
    #pragma unroll
    for (int kk = 0; kk < 8; ++kk) {
        f4 u0 = *(const f4*)(xr + kk * 32 + lkg * 8);
        f4 u1 = *(const f4*)(xr + kk * 32 + lkg * 8 + 4);
        unsigned apv[4];
        apv[0] = pk2(u0.x, u0.y); apv[1] = pk2(u0.z, u0.w);
        apv[2] = pk2(u1.x, u1.y); apv[3] = pk2(u1.z, u1.w);
        short8 afr = *reinterpret_cast<short8*>(apv);
        #pragma unroll
        for (int t = 0; t < 2; ++t) {
            short8 bfr = *(const short8*)(wa1T + ((t * 16 + cl) * 256 + kk * 32 + lkg * 8));
            acc1[t] = __builtin_amdgcn_mfma_f32_16x16x32_bf16(afr, bfr, acc1[t], 0, 0, 0);
        }
    }
    // C layout: row m = lkg*4+r (px = wv*16+m), col a = t*16+cl.
    // bounce via per-wave LDS (pitch 80 B), then one coalesced 16 B store/lane
    const unsigned a1base = (unsigned)wv * 1280u;
    #pragma unroll
    for (int t = 0; t < 2; ++t) {
        int a = t * 16 + cl;
        float bb = b_a1p[a];
        #pragma unroll
        for (int r = 0; r < 4; ++r) {
            float vv = acc1[t][r] + bb;
            vv = vv > 0.f ? vv : 0.f;
            int m = lkg * 4 + r;
            *(unsigned short*)(lds + a1base + m * 80 + a * 2) = f2bf(vv);
        }
    }
    asm volatile("s_waitcnt lgkmcnt(0)" ::: "memory");
    __builtin_amdgcn_sched_barrier(0);
    uint4 v = *(const uint4*)(lds + a1base + (lane >> 2) * 80 + (lane & 3) * 16);
    *(uint4*)(a1g + (size_t)row * 2048 + wv * 512 + lane * 8) = v;
}

// ---------------------------------------------------------------------------
// Kernel B: stage(from x) | barrier | {main GEMM interleaved with GEMM2+exp}
// | barrier | epilogue.  Block = one image row, 8 waves, 1024 blocks.
// Per wave: 32-f slice x 64 px (f-split main GEMM; e lane-local since GEMM2
// C-layout == main-GEMM C-layout).
// The GEMM2/exp work (feeds ONLY the epilogue) is interleaved into the main
// GEMM kk-loop: its L2 loads and exp VALU co-issue with the MFMA stream.
// LDS 34816: xs[0,32768) [64px][256c] bf16 XOR-swizzled;
//            psum[32768,34816) = [8 wv][64 px] f32.
// launch_bounds(512,4): VGPR budget 128 for real ILP (R9's (512,8) starved
// the allocator to 32 VGPR -> no loads in flight).
// ---------------------------------------------------------------------------
__global__ __launch_bounds__(512, 4)
void fused2_kernel(const float* __restrict__ x,
                   const unsigned short* __restrict__ a1g,
                   const float* __restrict__ b3,
                   const unsigned short* __restrict__ w3T,
                   const unsigned short* __restrict__ wa2T,
                   const float* __restrict__ b_a2p,
                   float* __restrict__ out)
{
    __shared__ __align__(16) unsigned char lds[34816];

    const int tid = threadIdx.x;
    const int bid = blockIdx.x;
    const int row = (bid & 7) * 128 + (bid >> 3);   // XCD swizzle
    const int h   = row & 63;

    const int wv   = tid >> 6;
    const int lane = tid & 63;
    const int cl   = lane & 15;
    const int lkg  = lane >> 4;
    const int F0   = wv * 32;

    const size_t rowb = (size_t)row * 16384;
    const float* xrow = x + rowb;
    const bool hm = (h > 0), hp = (h < 63);
    const f4* pc = (const f4*)xrow;
    const f4* pm = (const f4*)(xrow - 16384);
    const f4* pp = (const f4*)(xrow + 16384);
    const f4 z4 = {0.f, 0.f, 0.f, 0.f};

    // ------- stage own 8-px strip: rolling 3-reg window -> xs --------------
    {
        f4 w0 = z4, w1 = z4, w2 = z4;
        #pragma unroll
        for (int r = 0; r < 10; ++r) {
            int g = wv * 8 - 1 + r;
            f4 vr = z4;
            if (g >= 0 && g < 64) {
                int idx = g * 64 + lane;
                f4 a0 = pc[idx];
                f4 am = hm ? pm[idx] : z4;
                f4 ap = hp ? pp[idx] : z4;
                vr = a0 + am + ap;
            }
            w2 = vr;
            if (r >= 2) {
                f4 s = w0 + w1 + w2;
                int j = r - 2;                    // local row 0..7
                int gw = wv * 8 + j;              // gw & 7 == j
                unsigned addr = (unsigned)gw * 512u +
                                (((unsigned)lane * 8u) ^ (((unsigned)j & 7u) << 4));
                uint2 pk;
                pk.x = pk2(s.x, s.y);
                pk.y = pk2(s.z, s.w);
                *(uint2*)(lds + addr) = pk;
            }
            w0 = w1; w1 = w2;
        }
    }

    __syncthreads();   // xs published

    // ------- merged region: main GEMM + GEMM2/exp interleaved --------------
    f32x4 acc[2][4];
    #pragma unroll
    for (int ft = 0; ft < 2; ++ft)
        #pragma unroll
        for (int pt = 0; pt < 4; ++pt) acc[ft][pt] = (f32x4){0,0,0,0};

    uint2 ep[2][4];                    // e packed bf16
    float ps[4];                       // per-px-group softmax partial sums
    const unsigned short* a1row = a1g + (size_t)row * 2048;

    // GEMM2 weight frags (reused across all pt): 2 x short8 = 8 VGPR
    short8 wfr2[2];
    #pragma unroll
    for (int ft = 0; ft < 2; ++ft)
        wfr2[ft] = *(const short8*)(wa2T + ((F0 + ft * 16 + cl) * 32 + lkg * 8));
    f4 bb2[2];
    #pragma unroll
    for (int ft = 0; ft < 2; ++ft)
        bb2[ft] = *(const f4*)(b_a2p + F0 + ft * 16 + lkg * 4);

    #pragma unroll
    for (int kk = 0; kk < 8; ++kk) {
        // ---- main GEMM step ----
        short8 afr[2];
        #pragma unroll
        for (int ft = 0; ft < 2; ++ft)
            afr[ft] = *(const short8*)(w3T + ((F0 + ft * 16 + cl) * 256 + kk * 32 + lkg * 8));
        short8 xfr[4];
        #pragma unroll
        for (int pt = 0; pt < 4; ++pt) {
            unsigned px = (unsigned)(pt * 16 + cl);
            unsigned ad = px * 512u +
                          (((unsigned)(kk * 64 + lkg * 16)) ^ (((unsigned)px & 7u) << 4));
            xfr[pt] = *(const short8*)(lds + ad);
        }
        #pragma unroll
        for (int ft = 0; ft < 2; ++ft)
            #pragma unroll
            for (int pt = 0; pt < 4; ++pt)
                acc[ft][pt] = __builtin_amdgcn_mfma_f32_16x16x32_bf16(afr[ft], xfr[pt], acc[ft][pt], 0, 0, 0);

        // ---- GEMM2 pt-step on even kk: exp VALU overlaps MFMA pipe ----
        if ((kk & 1) == 0) {
            const int pt = kk >> 1;
            short8 bfr = *(const short8*)(a1row + ((pt * 16 + cl) * 32 + lkg * 8));
            f32x4 z = {0,0,0,0};
            f32x4 a2a = __builtin_amdgcn_mfma_f32_16x16x32_bf16(wfr2[0], bfr, z, 0, 0, 0);
            f32x4 a2b = __builtin_amdgcn_mfma_f32_16x16x32_bf16(wfr2[1], bfr, z, 0, 0, 0);
            float e0[4], e1[4];
            #pragma unroll
            for (int r = 0; r < 4; ++r) {
                float va = a2a[r] + bb2[0][r]; va = va > 0.f ? va : 0.f;
                float vb = a2b[r] + bb2[1][r]; vb = vb > 0.f ? vb : 0.f;
                e0[r] = __expf(va);
                e1[r] = __expf(vb);
            }
            ep[0][pt].x = pk2(e0[0], e0[1]); ep[0][pt].y = pk2(e0[2], e0[3]);
            ep[1][pt].x = pk2(e1[0], e1[1]); ep[1][pt].y = pk2(e1[2], e1[3]);
            float s = ((e0[0] + e0[1]) + (e0[2] + e0[3]))
                    + ((e1[0] + e1[1]) + (e1[2] + e1[3]));
            s += __shfl_xor(s, 16);
            s += __shfl_xor(s, 32);
            ps[pt] = s;               // replicated across lkg
        }
    }

    // one psum writer per px: lane with lkg==pt writes px = lkg*16+cl = lane
    {
        float wsum = (lkg == 0) ? ps[0] : (lkg == 1) ? ps[1]
                   : (lkg == 2) ? ps[2] : ps[3];
        *(float*)(lds + 32768 + wv * 256 + lane * 4) = wsum;
    }

    __syncthreads();   // psum published

    // ------- epilogue: o = e * invS * (s + cnt*b3) -------------------------
    const int rh = (h == 0 || h == 63) ? 2 : 3;
    f4 b3v[2];
    #pragma unroll
    for (int ft = 0; ft < 2; ++ft)
        b3v[ft] = *(const f4*)(b3 + F0 + ft * 16 + lkg * 4);
    #pragma unroll
    for (int pt = 0; pt < 4; ++pt) {
        int px = pt * 16 + cl;
        float den = 0.f;
        #pragma unroll
        for (int w = 0; w < 8; ++w)
            den += *(const float*)(lds + 32768 + w * 256 + px * 4);
        float is = 1.f / den;
        float cnt = (float)(rh * ((px == 0 || px == 63) ? 2 : 3));
        #pragma unroll
        for (int ft = 0; ft < 2; ++ft) {
            int f0 = F0 + ft * 16 + lkg * 4;
            uint2 ev = ep[ft][pt];
            f4 o;
            o.x = bf2f(ev.x & 0xffffu) * is * (acc[ft][pt][0] + cnt * b3v[ft].x);
            o.y = bf2f(ev.x >> 16)     * is * (acc[ft][pt][1] + cnt * b3v[ft].y);
            o.z = bf2f(ev.y & 0xffffu) * is * (acc[ft][pt][2] + cnt * b3v[ft].z);
            o.w = bf2f(ev.y >> 16)     * is * (acc[ft][pt][3] + cnt * b3v[ft].w);
            *(f4*)(out + rowb + (size_t)px * 256 + f0) = o;
        }
    }
}

extern "C" void kernel_launch(void* const* d_in, const int* in_sizes, int n_in,
                              void* d_out, int out_size, void* d_ws, size_t ws_size,
                              hipStream_t stream)
{
    const float* x   = (const float*)d_in[0];
    const float* w3  = (const float*)d_in[1];
    const float* b3  = (const float*)d_in[2];
    const float* g1  = (const float*)d_in[3];
    const float* be1 = (const float*)d_in[4];
    const float* m1  = (const float*)d_in[5];
    const float* v1  = (const float*)d_in[6];
    const float* wa1 = (const float*)d_in[7];
    const float* ba1 = (const float*)d_in[8];
    const float* g2  = (const float*)d_in[9];
    const float* be2 = (const float*)d_in[10];
    const float* m2  = (const float*)d_in[11];
    const float* v2  = (const float*)d_in[12];
    const float* wa2 = (const float*)d_in[13];
    const float* ba2 = (const float*)d_in[14];

    unsigned char* ws = (unsigned char*)d_ws;
    unsigned short* w3T   = (unsigned short*)(ws);
    unsigned short* wa1T  = (unsigned short*)(ws + 131072);
    unsigned short* wa2T  = (unsigned short*)(ws + 147456);
    float*          b_a1p = (float*)(ws + 163840);
    float*          b_a2p = (float*)(ws + 163968);
    unsigned short* a1g   = (unsigned short*)(ws + 196608);   // 4 MB

    hipLaunchKernelGGL(prep_kernel, dim3(97), dim3(256), 0, stream,
                       w3, g1, be1, m1, v1, wa1, ba1, g2, be2, m2, v2, wa2, ba2,
                       w3T, wa1T, wa2T, b_a1p, b_a2p);
    hipLaunchKernelGGL(attn1_kernel, dim3(1024), dim3(256), 0, stream,
                       x, wa1T, b_a1p, a1g);
    hipLaunchKernelGGL(fused2_kernel, dim3(1024), dim3(512), 0, stream,
                       x, a1g, b3, w3T, wa2T, b_a2p, (float*)d_out);
}

// Round 11
// 67.654 us; speedup vs baseline: 1.1753x; 1.0157x over previous
//
#include <hip/hip_runtime.h>
#include <hip/hip_bf16.h>

#define EPS 1e-3f

typedef float f32x4 __attribute__((ext_vector_type(4)));
typedef float f4    __attribute__((ext_vector_type(4)));
typedef short short8 __attribute__((ext_vector_type(8)));

__device__ __forceinline__ unsigned short f2bf(float f) {
    unsigned u = __float_as_uint(f);
    u += 0x7FFFu + ((u >> 16) & 1u);   // round-to-nearest-even
    return (unsigned short)(u >> 16);
}
__device__ __forceinline__ float bf2f(unsigned s) {
    return __uint_as_float(s << 16);
}
// packed f32x2 -> bf16x2 (RNE)
__device__ __forceinline__ unsigned pk2(float lo, float hi) {
    float2 t; t.x = lo; t.y = hi;
    __hip_bfloat162 hh = __float22bfloat162_rn(t);
    return *reinterpret_cast<unsigned*>(&hh);
}

// ---------------------------------------------------------------------------
// Prep: fold BN1/BN2 into attention weights, transpose all weights to bf16
// ---------------------------------------------------------------------------
__global__ void prep_kernel(const float* __restrict__ w3,
                            const float* __restrict__ g1, const float* __restrict__ be1,
                            const float* __restrict__ m1, const float* __restrict__ v1,
                            const float* __restrict__ wa1, const float* __restrict__ ba1,
                            const float* __restrict__ g2, const float* __restrict__ be2,
                            const float* __restrict__ m2, const float* __restrict__ v2,
                            const float* __restrict__ wa2, const float* __restrict__ ba2,
                            unsigned short* __restrict__ w3T,
                            unsigned short* __restrict__ wa1T,
                            unsigned short* __restrict__ wa2T,
                            float* __restrict__ b_a1p, float* __restrict__ b_a2p)
{
    const int blk = blockIdx.x;
    const int tid = threadIdx.x;
    if (blk < 64) {
        #pragma unroll
        for (int i = 0; i < 4; ++i) {
            int f = blk * 4 + i;
            w3T[f * 256 + tid] = f2bf(w3[tid * 256 + f]);
        }
    } else if (blk < 96) {
        int a = blk - 64;
        int c = tid;
        float s1 = rsqrtf(v1[c] + EPS) * g1[c];
        float wv = wa1[c * 32 + a];
        wa1T[a * 256 + c] = f2bf(wv * s1);
        float part = (be1[c] - m1[c] * s1) * wv;
        __shared__ float red[4];
        #pragma unroll
        for (int off = 32; off > 0; off >>= 1) part += __shfl_down(part, off);
        if ((tid & 63) == 0) red[tid >> 6] = part;
        __syncthreads();
        if (tid == 0) b_a1p[a] = ba1[a] + red[0] + red[1] + red[2] + red[3];
    } else {
        int f = tid;
        float acc = ba2[f];
        #pragma unroll
        for (int a = 0; a < 32; ++a) {
            float s2 = rsqrtf(v2[a] + EPS) * g2[a];
            float wv = wa2[a * 256 + f];
            wa2T[f * 32 + a] = f2bf(wv * s2);
            acc += (be2[a] - m2[a] * s2) * wv;
        }
        b_a2p[f] = acc;
    }
}

// ---------------------------------------------------------------------------
// Kernel A: a1 = relu(x_bn @ wa1')  [65536 px x 32], bf16 out to workspace.
// Block = one image row, 4 waves x 16 px. Tiny LDS (5 KB bounce), no barrier.
// a1g layout: [row 0..1023][px 0..63][a 0..31] bf16 (4 KB per row).
// ---------------------------------------------------------------------------
__global__ __launch_bounds__(256, 8)
void attn1_kernel(const float* __restrict__ x,
                  const unsigned short* __restrict__ wa1T,
                  const float* __restrict__ b_a1p,
                  unsigned short* __restrict__ a1g)
{
    __shared__ __align__(16) unsigned char lds[5120];

    const int tid = threadIdx.x;
    const int bid = blockIdx.x;
    const int row = (bid & 7) * 128 + (bid >> 3);   // XCD swizzle

    const int wv   = tid >> 6;
    const int lane = tid & 63;
    const int cl   = lane & 15;
    const int lkg  = lane >> 4;

    const float* xr = x + ((size_t)row * 64 + wv * 16 + cl) * 256;

    f32x4 acc1[2];
    acc1[0] = (f32x4){0,0,0,0};
    acc1[1] = (f32x4){0,0,0,0};
    #pragma unroll
    for (int kk = 0; kk < 8; ++kk) {
        f4 u0 = *(const f4*)(xr + kk * 32 + lkg * 8);
        f4 u1 = *(const f4*)(xr + kk * 32 + lkg * 8 + 4);
        unsigned apv[4];
        apv[0] = pk2(u0.x, u0.y); apv[1] = pk2(u0.z, u0.w);
        apv[2] = pk2(u1.x, u1.y); apv[3] = pk2(u1.z, u1.w);
        short8 afr = *reinterpret_cast<short8*>(apv);
        #pragma unroll
        for (int t = 0; t < 2; ++t) {
            short8 bfr = *(const short8*)(wa1T + ((t * 16 + cl) * 256 + kk * 32 + lkg * 8));
            acc1[t] = __builtin_amdgcn_mfma_f32_16x16x32_bf16(afr, bfr, acc1[t], 0, 0, 0);
        }
    }
    // C layout: row m = lkg*4+r (px = wv*16+m), col a = t*16+cl.
    // bounce via per-wave LDS (pitch 80 B), then one coalesced 16 B store/lane
    const unsigned a1base = (unsigned)wv * 1280u;
    #pragma unroll
    for (int t = 0; t < 2; ++t) {
        int a = t * 16 + cl;
        float bb = b_a1p[a];
        #pragma unroll
        for (int r = 0; r < 4; ++r) {
            float vv = acc1[t][r] + bb;
            vv = vv > 0.f ? vv : 0.f;
            int m = lkg * 4 + r;
            *(unsigned short*)(lds + a1base + m * 80 + a * 2) = f2bf(vv);
        }
    }
    asm volatile("s_waitcnt lgkmcnt(0)" ::: "memory");
    __builtin_amdgcn_sched_barrier(0);
    uint4 v = *(const uint4*)(lds + a1base + (lane >> 2) * 80 + (lane & 3) * 16);
    *(uint4*)(a1g + (size_t)row * 2048 + wv * 512 + lane * 8) = v;
}

// ---------------------------------------------------------------------------
// Kernel B: stage(from x, ILP-batched) | barrier | {main GEMM + GEMM2/exp
// interleaved} | barrier | epilogue.  Block = one image row, 8 waves.
// Stage: ALL 30 independent f4 loads issued via named unrolled arrays
// (compile-time indices only) so the compiler must batch them -> ~20+
// outstanding instead of R10's ~4 (VGPR 56).  Per wave: 32-f slice x 64 px.
// LDS 34816: xs[0,32768) [64px][256c] bf16 XOR-swizzled;
//            psum[32768,34816) = [8 wv][64 px] f32.
// ---------------------------------------------------------------------------
__global__ __launch_bounds__(512, 4)
void fused2_kernel(const float* __restrict__ x,
                   const unsigned short* __restrict__ a1g,
                   const float* __restrict__ b3,
                   const unsigned short* __restrict__ w3T,
                   const unsigned short* __restrict__ wa2T,
                   const float* __restrict__ b_a2p,
                   float* __restrict__ out)
{
    __shared__ __align__(16) unsigned char lds[34816];

    const int tid = threadIdx.x;
    const int bid = blockIdx.x;
    const int row = (bid & 7) * 128 + (bid >> 3);   // XCD swizzle
    const int h   = row & 63;

    const int wv   = tid >> 6;
    const int lane = tid & 63;
    const int cl   = lane & 15;
    const int lkg  = lane >> 4;
    const int F0   = wv * 32;

    const size_t rowb = (size_t)row * 16384;
    const float* xrow = x + rowb;
    const bool hm = (h > 0), hp = (h < 63);
    const f4* pc = (const f4*)xrow;
    const f4* pm = (const f4*)(xrow - 16384);
    const f4* pp = (const f4*)(xrow + 16384);
    const f4 z4 = {0.f, 0.f, 0.f, 0.f};

    // ------- stage own 8-px strip: batched independent loads -> xs ---------
    {
        f4 lm[10], lc[10], lp[10];
        #pragma unroll
        for (int r = 0; r < 10; ++r) {
            int g  = wv * 8 - 1 + r;
            int gc = g < 0 ? 0 : (g > 63 ? 63 : g);
            int idx = gc * 64 + lane;
            lc[r] = pc[idx];
            lm[r] = hm ? pm[idx] : z4;
            lp[r] = hp ? pp[idx] : z4;
        }
        f4 vs[10];
        #pragma unroll
        for (int r = 0; r < 10; ++r) {
            int g = wv * 8 - 1 + r;
            f4 v = lm[r] + lc[r] + lp[r];
            vs[r] = (g >= 0 && g < 64) ? v : z4;
        }
        #pragma unroll
        for (int j = 0; j < 8; ++j) {
            f4 s = vs[j] + vs[j + 1] + vs[j + 2];
            int gw = wv * 8 + j;              // gw & 7 == j
            unsigned addr = (unsigned)gw * 512u +
                            (((unsigned)lane * 8u) ^ (((unsigned)j & 7u) << 4));
            uint2 pk;
            pk.x = pk2(s.x, s.y);
            pk.y = pk2(s.z, s.w);
            *(uint2*)(lds + addr) = pk;
        }
    }

    __syncthreads();   // xs published

    // ------- merged region: main GEMM + GEMM2/exp interleaved --------------
    f32x4 acc[2][4];
    #pragma unroll
    for (int ft = 0; ft < 2; ++ft)
        #pragma unroll
        for (int pt = 0; pt < 4; ++pt) acc[ft][pt] = (f32x4){0,0,0,0};

    uint2 ep[2][4];                    // e packed bf16
    float ps[4];                       // per-px-group softmax partial sums
    const unsigned short* a1row = a1g + (size_t)row * 2048;

    // GEMM2 weight frags (reused across all pt): 2 x short8 = 8 VGPR
    short8 wfr2[2];
    #pragma unroll
    for (int ft = 0; ft < 2; ++ft)
        wfr2[ft] = *(const short8*)(wa2T + ((F0 + ft * 16 + cl) * 32 + lkg * 8));
    f4 bb2[2];
    #pragma unroll
    for (int ft = 0; ft < 2; ++ft)
        bb2[ft] = *(const f4*)(b_a2p + F0 + ft * 16 + lkg * 4);

    #pragma unroll
    for (int kk = 0; kk < 8; ++kk) {
        // ---- main GEMM step ----
        short8 afr[2];
        #pragma unroll
        for (int ft = 0; ft < 2; ++ft)
            afr[ft] = *(const short8*)(w3T + ((F0 + ft * 16 + cl) * 256 + kk * 32 + lkg * 8));
        short8 xfr[4];
        #pragma unroll
        for (int pt = 0; pt < 4; ++pt) {
            unsigned px = (unsigned)(pt * 16 + cl);
            unsigned ad = px * 512u +
                          (((unsigned)(kk * 64 + lkg * 16)) ^ (((unsigned)px & 7u) << 4));
            xfr[pt] = *(const short8*)(lds + ad);
        }
        #pragma unroll
        for (int ft = 0; ft < 2; ++ft)
            #pragma unroll
            for (int pt = 0; pt < 4; ++pt)
                acc[ft][pt] = __builtin_amdgcn_mfma_f32_16x16x32_bf16(afr[ft], xfr[pt], acc[ft][pt], 0, 0, 0);

        // ---- GEMM2 pt-step on even kk: exp VALU overlaps MFMA pipe ----
        if ((kk & 1) == 0) {
            const int pt = kk >> 1;
            short8 bfr = *(const short8*)(a1row + ((pt * 16 + cl) * 32 + lkg * 8));
            f32x4 z = {0,0,0,0};
            f32x4 a2a = __builtin_amdgcn_mfma_f32_16x16x32_bf16(wfr2[0], bfr, z, 0, 0, 0);
            f32x4 a2b = __builtin_amdgcn_mfma_f32_16x16x32_bf16(wfr2[1], bfr, z, 0, 0, 0);
            float e0[4], e1[4];
            #pragma unroll
            for (int r = 0; r < 4; ++r) {
                float va = a2a[r] + bb2[0][r]; va = va > 0.f ? va : 0.f;
                float vb = a2b[r] + bb2[1][r]; vb = vb > 0.f ? vb : 0.f;
                e0[r] = __expf(va);
                e1[r] = __expf(vb);
            }
            ep[0][pt].x = pk2(e0[0], e0[1]); ep[0][pt].y = pk2(e0[2], e0[3]);
            ep[1][pt].x = pk2(e1[0], e1[1]); ep[1][pt].y = pk2(e1[2], e1[3]);
            float s = ((e0[0] + e0[1]) + (e0[2] + e0[3]))
                    + ((e1[0] + e1[1]) + (e1[2] + e1[3]));
            s += __shfl_xor(s, 16);
            s += __shfl_xor(s, 32);
            ps[pt] = s;               // replicated across lkg
        }
    }

    // one psum writer per px: lane with lkg==pt writes px = lkg*16+cl = lane
    {
        float wsum = (lkg == 0) ? ps[0] : (lkg == 1) ? ps[1]
                   : (lkg == 2) ? ps[2] : ps[3];
        *(float*)(lds + 32768 + wv * 256 + lane * 4) = wsum;
    }

    __syncthreads();   // psum published

    // ------- epilogue: o = e * invS * (s + cnt*b3) -------------------------
    const int rh = (h == 0 || h == 63) ? 2 : 3;
    f4 b3v[2];
    #pragma unroll
    for (int ft = 0; ft < 2; ++ft)
        b3v[ft] = *(const f4*)(b3 + F0 + ft * 16 + lkg * 4);
    #pragma unroll
    for (int pt = 0; pt < 4; ++pt) {
        int px = pt * 16 + cl;
        float den = 0.f;
        #pragma unroll
        for (int w = 0; w < 8; ++w)
            den += *(const float*)(lds + 32768 + w * 256 + px * 4);
        float is = 1.f / den;
        float cnt = (float)(rh * ((px == 0 || px == 63) ? 2 : 3));
        #pragma unroll
        for (int ft = 0; ft < 2; ++ft) {
            int f0 = F0 + ft * 16 + lkg * 4;
            uint2 ev = ep[ft][pt];
            f4 o;
            o.x = bf2f(ev.x & 0xffffu) * is * (acc[ft][pt][0] + cnt * b3v[ft].x);
            o.y = bf2f(ev.x >> 16)     * is * (acc[ft][pt][1] + cnt * b3v[ft].y);
            o.z = bf2f(ev.y & 0xffffu) * is * (acc[ft][pt][2] + cnt * b3v[ft].z);
            o.w = bf2f(ev.y >> 16)     * is * (acc[ft][pt][3] + cnt * b3v[ft].w);
            *(f4*)(out + rowb + (size_t)px * 256 + f0) = o;
        }
    }
}

extern "C" void kernel_launch(void* const* d_in, const int* in_sizes, int n_in,
                              void* d_out, int out_size, void* d_ws, size_t ws_size,
                              hipStream_t stream)
{
    const float* x   = (const float*)d_in[0];
    const float* w3  = (const float*)d_in[1];
    const float* b3  = (const float*)d_in[2];
    const float* g1  = (const float*)d_in[3];
    const float* be1 = (const float*)d_in[4];
    const float* m1  = (const float*)d_in[5];
    const float* v1  = (const float*)d_in[6];
    const float* wa1 = (const float*)d_in[7];
    const float* ba1 = (const float*)d_in[8];
    const float* g2  = (const float*)d_in[9];
    const float* be2 = (const float*)d_in[10];
    const float* m2  = (const float*)d_in[11];
    const float* v2  = (const float*)d_in[12];
    const float* wa2 = (const float*)d_in[13];
    const float* ba2 = (const float*)d_in[14];

    unsigned char* ws = (unsigned char*)d_ws;
    unsigned short* w3T   = (unsigned short*)(ws);
    unsigned short* wa1T  = (unsigned short*)(ws + 131072);
    unsigned short* wa2T  = (unsigned short*)(ws + 147456);
    float*          b_a1p = (float*)(ws + 163840);
    float*          b_a2p = (float*)(ws + 163968);
    unsigned short* a1g   = (unsigned short*)(ws + 196608);   // 4 MB

    hipLaunchKernelGGL(prep_kernel, dim3(97), dim3(256), 0, stream,
                       w3, g1, be1, m1, v1, wa1, ba1, g2, be2, m2, v2, wa2, ba2,
                       w3T, wa1T, wa2T, b_a1p, b_a2p);
    hipLaunchKernelGGL(attn1_kernel, dim3(1024), dim3(256), 0, stream,
                       x, wa1T, b_a1p, a1g);
    hipLaunchKernelGGL(fused2_kernel, dim3(1024), dim3(512), 0, stream,
                       x, a1g, b3, w3T, wa2T, b_a2p, (float*)d_out);
}